// Round 6
// baseline (2729.699 us; speedup 1.0000x reference)
//
#include <hip/hip_runtime.h>
#include <hip/hip_fp16.h>

#define NNODE 10000
#define NEDGE 160000
#define W32 32
#define BSTR 40          // f16 row stride for h2 B panels (80 B, 16B-aligned)
#define PANEL_F16 10240  // h2 panels: 256 cols * 40

typedef _Float16 f16;
typedef _Float16 f16x8 __attribute__((ext_vector_type(8)));
typedef float f32x4 __attribute__((ext_vector_type(4)));

// ---- stage one 20480-B panel (1280 slots): wave w does slots [w*320, w*320+320) ----
__device__ __forceinline__ void stage_panel(f16* lds, const f16* g, int w, int lane) {
    #pragma unroll
    for (int i = 0; i < 5; ++i) {
        int slot = w * 320 + i * 64 + lane;
        __builtin_amdgcn_global_load_lds(
            (const __attribute__((address_space(1))) unsigned int*)(g + (size_t)slot * 8),
            (__attribute__((address_space(3))) unsigned int*)(lds + (size_t)(w * 320 + i * 64) * 8),
            16, 0, 0);
    }
}

// ================= weight packs =================
__global__ __launch_bounds__(256) void pack_k1(const float* __restrict__ k1w, f16* __restrict__ k1p) {
    int t = blockIdx.x * 256 + threadIdx.x;           // 10240
    int j = t / BSTR, c = t % BSTR;
    k1p[t] = (c < 6) ? (f16)k1w[c * 256 + j] : (f16)0.f;
}
__global__ __launch_bounds__(256) void pack_k2(const float* __restrict__ k2w, f16* __restrict__ k2p) {
    int t = blockIdx.x * 256 + threadIdx.x;           // 8*10240
    int kk = t / PANEL_F16, r = t % PANEL_F16;
    int j = r / BSTR, c = r % BSTR;
    k2p[t] = (c < 32) ? (f16)k2w[(size_t)(kk * 32 + c) * 256 + j] : (f16)0.f;
}
// k3r[col][k] col-major: k3r[col*256+k] = k3w[k][col]   (1024 cols, 256 k)
__global__ __launch_bounds__(256) void pack_k3(const float* __restrict__ k3w, f16* __restrict__ k3r) {
    int i = blockIdx.x * 256 + threadIdx.x;           // 262144, i = k*1024+col (coalesced read)
    int k = i >> 10, col = i & 1023;
    k3r[(size_t)col * 256 + k] = (f16)k3w[i];
}

// ================= h2 = relu(relu(ea@k1+b1)@k2+b2), fp16 out (verified r4/r5) =============
__global__ __launch_bounds__(256) void h2_kernel(
    const float* __restrict__ ea,
    const f16* __restrict__ k1p, const float* __restrict__ k1b,
    const f16* __restrict__ k2p, const float* __restrict__ k2b,
    f16* __restrict__ h2c, int e_start)
{
    __shared__ __align__(16) f16 bls[256 * BSTR];
    __shared__ __align__(16) f16 ea_s[64 * BSTR];
    __shared__ __align__(16) f16 hbuf[64 * 264];

    const int t = threadIdx.x, w = t >> 6, lane = t & 63, quad = lane >> 4, l15 = lane & 15;
    const int el0 = blockIdx.x * 64;
    const int e0 = e_start + el0;

    for (int i = t; i < 64 * BSTR; i += 256) {
        int e = i / BSTR, c = i % BSTR;
        ea_s[i] = (f16)((c < 6) ? ea[(size_t)(e0 + e) * 6 + c] : 0.f);
    }
    stage_panel(bls, k1p, w, lane);
    __syncthreads();

    f16x8 a1 = *(const f16x8*)&ea_s[(w * 16 + l15) * BSTR + quad * 8];
    f32x4 acc[16];
    #pragma unroll
    for (int nt = 0; nt < 16; ++nt) { float b = k1b[nt * 16 + l15]; acc[nt] = (f32x4){b, b, b, b}; }
    #pragma unroll
    for (int nt = 0; nt < 16; ++nt) {
        f16x8 bf = *(const f16x8*)&bls[(nt * 16 + l15) * BSTR + quad * 8];
        acc[nt] = __builtin_amdgcn_mfma_f32_16x16x32_f16(a1, bf, acc[nt], 0, 0, 0);
    }
    __syncthreads();
    #pragma unroll
    for (int nt = 0; nt < 16; ++nt)
        #pragma unroll
        for (int r = 0; r < 4; ++r)
            hbuf[(w * 16 + quad * 4 + r) * 264 + nt * 16 + l15] = (f16)fmaxf(acc[nt][r], 0.f);
    __syncthreads();

    f16x8 a2[8];
    #pragma unroll
    for (int kk = 0; kk < 8; ++kk)
        a2[kk] = *(const f16x8*)&hbuf[(w * 16 + l15) * 264 + kk * 32 + quad * 8];
    #pragma unroll
    for (int nt = 0; nt < 16; ++nt) { float b = k2b[nt * 16 + l15]; acc[nt] = (f32x4){b, b, b, b}; }
    for (int kk = 0; kk < 8; ++kk) {
        __syncthreads();
        stage_panel(bls, k2p + (size_t)kk * PANEL_F16, w, lane);
        __syncthreads();
        #pragma unroll
        for (int nt = 0; nt < 16; ++nt) {
            f16x8 bf = *(const f16x8*)&bls[(nt * 16 + l15) * BSTR + quad * 8];
            acc[nt] = __builtin_amdgcn_mfma_f32_16x16x32_f16(a2[kk], bf, acc[nt], 0, 0, 0);
        }
    }
    #pragma unroll
    for (int nt = 0; nt < 16; ++nt)
        #pragma unroll
        for (int r = 0; r < 4; ++r)
            h2c[(size_t)(el0 + w * 16 + quad * 4 + r) * 256 + nt * 16 + l15] = (f16)fmaxf(acc[nt][r], 0.f);
}

// ========== fused msg: waves split N (i-slices), B from L2 regs, LDS cross-wave reduce ====
// 128 edges/block. Wave w owns k3 cols [w*256, w*256+256) i.e. i in [w*8, w*8+8).
// M-blocks of 32 edges (2 tiles), N-blocks of 32 cols (2 tiles = one i), K = 8 steps of 32.
__global__ __launch_bounds__(256, 2) void msg_fused(
    const int* __restrict__ ei, const f16* __restrict__ h2c,
    const f16* __restrict__ k3r, const float* __restrict__ k3b,
    const float* __restrict__ h, float* __restrict__ agg, int e_start)
{
    __shared__ __align__(16) f16 h_s[128 * 40];       // 10240 B, stride 40 (16B-aligned f16x8)
    __shared__ float msgred[4 * 32 * 33];             // 16.9 KB cross-wave partials
    __shared__ int dst_s[128];

    const int t = threadIdx.x, w = t >> 6, lane = t & 63, quad = lane >> 4, l15 = lane & 15;
    const int el0 = blockIdx.x * 128;                 // chunk-local
    const int e0 = e_start + el0;                     // global

    if (t < 128) dst_s[t] = ei[NEDGE + e0 + t];
    {   // gather h[src] as fp16: 2 threads per edge row
        int e = t >> 1, half = t & 1;
        int srcn = ei[e0 + e];
        const float4* hr = (const float4*)(h + (size_t)srcn * 32 + half * 16);
        f16* dp = &h_s[e * 40 + half * 16];
        #pragma unroll
        for (int qq = 0; qq < 4; ++qq) {
            float4 v = hr[qq];
            dp[qq * 4 + 0] = (f16)v.x; dp[qq * 4 + 1] = (f16)v.y;
            dp[qq * 4 + 2] = (f16)v.z; dp[qq * 4 + 3] = (f16)v.w;
        }
    }

    // per-wave bias for its 16 N-tiles (cols w*256 + nt2*32 + n*16 + l15)
    float bias[8][2];
    #pragma unroll
    for (int nt2 = 0; nt2 < 8; ++nt2) {
        bias[nt2][0] = k3b[w * 256 + nt2 * 32 + l15];
        bias[nt2][1] = k3b[w * 256 + nt2 * 32 + 16 + l15];
    }
    __syncthreads();                                  // h_s / dst_s ready

    for (int mt2 = 0; mt2 < 4; ++mt2) {
        // A double-tile (32 edges, all K) from global h2c (L2/L3-resident)
        f16x8 a[2][8];
        #pragma unroll
        for (int m = 0; m < 2; ++m)
            #pragma unroll
            for (int kk = 0; kk < 8; ++kk)
                a[m][kk] = *(const f16x8*)(h2c +
                    (size_t)(el0 + mt2 * 32 + m * 16 + l15) * 256 + kk * 32 + quad * 8);

        // h fragments for these 32 edges, this wave's 8 i-values (LDS broadcast reads)
        f16x8 hr8[2][4];
        #pragma unroll
        for (int m = 0; m < 2; ++m)
            #pragma unroll
            for (int r = 0; r < 4; ++r)
                hr8[m][r] = *(const f16x8*)&h_s[(mt2 * 32 + m * 16 + quad * 4 + r) * 40 + w * 8];

        float msgp[2][4][2];
        #pragma unroll
        for (int m = 0; m < 2; ++m)
            #pragma unroll
            for (int r = 0; r < 4; ++r) { msgp[m][r][0] = 0.f; msgp[m][r][1] = 0.f; }

        #pragma unroll
        for (int nt2 = 0; nt2 < 8; ++nt2) {
            // B double-tile (32 cols, all K) straight from L2 into registers
            f16x8 b[2][8];
            #pragma unroll
            for (int n = 0; n < 2; ++n)
                #pragma unroll
                for (int kk = 0; kk < 8; ++kk)
                    b[n][kk] = *(const f16x8*)(k3r +
                        (size_t)(w * 256 + nt2 * 32 + n * 16 + l15) * 256 + kk * 32 + quad * 8);

            f32x4 acc[2][2];
            #pragma unroll
            for (int m = 0; m < 2; ++m)
                #pragma unroll
                for (int n = 0; n < 2; ++n) {
                    float bv = bias[nt2][n];
                    acc[m][n] = (f32x4){bv, bv, bv, bv};
                }
            #pragma unroll
            for (int kk = 0; kk < 8; ++kk) {
                acc[0][0] = __builtin_amdgcn_mfma_f32_16x16x32_f16(a[0][kk], b[0][kk], acc[0][0], 0, 0, 0);
                acc[0][1] = __builtin_amdgcn_mfma_f32_16x16x32_f16(a[0][kk], b[1][kk], acc[0][1], 0, 0, 0);
                acc[1][0] = __builtin_amdgcn_mfma_f32_16x16x32_f16(a[1][kk], b[0][kk], acc[1][0], 0, 0, 0);
                acc[1][1] = __builtin_amdgcn_mfma_f32_16x16x32_f16(a[1][kk], b[1][kk], acc[1][1], 0, 0, 0);
            }
            // fold: this nt2 is i = w*8 + nt2; o = (n)*16 + l15
            #pragma unroll
            for (int m = 0; m < 2; ++m)
                #pragma unroll
                for (int r = 0; r < 4; ++r) {
                    float hv = (float)hr8[m][r][nt2];
                    msgp[m][r][0] += hv * acc[m][0][r];
                    msgp[m][r][1] += hv * acc[m][1][r];
                }
        }

        // cross-wave reduce via LDS, then one atomic per (edge, o)
        #pragma unroll
        for (int m = 0; m < 2; ++m)
            #pragma unroll
            for (int r = 0; r < 4; ++r) {
                int row = m * 16 + quad * 4 + r;
                msgred[w * 1056 + row * 33 + l15]      = msgp[m][r][0];
                msgred[w * 1056 + row * 33 + 16 + l15] = msgp[m][r][1];
            }
        __syncthreads();
        #pragma unroll
        for (int it = 0; it < 4; ++it) {
            int idx = it * 256 + t;                   // 1024 = 32 edges * 32 o
            int row = idx >> 5, o = idx & 31;
            float s = msgred[row * 33 + o] + msgred[1056 + row * 33 + o]
                    + msgred[2112 + row * 33 + o] + msgred[3168 + row * 33 + o];
            atomicAdd(&agg[dst_s[mt2 * 32 + row] * W32 + o], s);
        }
        __syncthreads();                              // msgred free for next mt2
    }
}

// ================= small kernels =================
__global__ __launch_bounds__(256) void h0_kernel(
    const float* __restrict__ x, const float* __restrict__ fc1w,
    const float* __restrict__ fc1b, float* __restrict__ h)
{
    int idx = blockIdx.x * 256 + threadIdx.x;
    int n = idx >> 5, j = idx & 31;
    h[idx] = x[n] * fc1w[j] + fc1b[j];
}

__global__ __launch_bounds__(256) void deg_kernel(
    const int* __restrict__ ei, float* __restrict__ deg)
{
    int e = blockIdx.x * 256 + threadIdx.x;
    if (e < NEDGE) atomicAdd(&deg[ei[NEDGE + e]], 1.f);
}

__global__ __launch_bounds__(256) void update_kernel(
    const float* __restrict__ h_old, float* __restrict__ h_new,
    float* __restrict__ agg, const float* __restrict__ deg,
    const float* __restrict__ rootw, const float* __restrict__ convb)
{
    __shared__ float rw[W32][W32 + 1];
    const int t = threadIdx.x;
    for (int q = t; q < W32 * W32; q += 256)
        rw[q >> 5][q & 31] = rootw[q];
    __syncthreads();
    const int nl = t >> 5, j = t & 31;
    const int n = blockIdx.x * 8 + nl;
    float hv = h_old[n * W32 + j];
    float acc = convb[j];
    #pragma unroll
    for (int k = 0; k < W32; ++k)
        acc += __shfl(hv, k, 32) * rw[k][j];
    float inv = 1.f / fmaxf(deg[n], 1.f);
    int idx = n * W32 + j;
    float a = agg[idx];
    agg[idx] = 0.f;
    h_new[idx] = fmaxf(a * inv + acc, 0.f);
}

__global__ __launch_bounds__(256) void out_kernel(
    const float* __restrict__ h, const float* __restrict__ fc2w,
    const float* __restrict__ fc2b, float* __restrict__ out)
{
    int n = blockIdx.x * 256 + threadIdx.x;
    if (n < NNODE) {
        float a = fc2b[0];
        #pragma unroll
        for (int j = 0; j < W32; ++j)
            a += h[n * W32 + j] * fc2w[j];
        out[n] = a;
    }
}

extern "C" void kernel_launch(void* const* d_in, const int* in_sizes, int n_in,
                              void* d_out, int out_size, void* d_ws, size_t ws_size,
                              hipStream_t stream) {
    const float* x    = (const float*)d_in[0];
    const int*   ei   = (const int*)  d_in[1];
    const float* ea   = (const float*)d_in[2];
    const float* fc1w = (const float*)d_in[3];
    const float* fc1b = (const float*)d_in[4];
    const float* k1w  = (const float*)d_in[5];
    const float* k1b  = (const float*)d_in[6];
    const float* k2w  = (const float*)d_in[7];
    const float* k2b  = (const float*)d_in[8];
    const float* k3w  = (const float*)d_in[9];
    const float* k3b  = (const float*)d_in[10];
    const float* rootw= (const float*)d_in[11];
    const float* convb= (const float*)d_in[12];
    const float* fc2w = (const float*)d_in[13];
    const float* fc2b = (const float*)d_in[14];
    float* out = (float*)d_out;

    const size_t hbytes = (size_t)NNODE * W32 * 4;
    char* ws = (char*)d_ws;
    size_t off = 0;
    float* hA  = (float*)(ws + off); off += hbytes;
    float* hB  = (float*)(ws + off); off += hbytes;
    float* agg = (float*)(ws + off); off += hbytes;
    float* deg = (float*)(ws + off); off += 40960;
    f16*  k1p  = (f16*)(ws + off);   off += 20480;
    f16*  k2p  = (f16*)(ws + off);   off += 163840;
    f16*  k3r  = (f16*)(ws + off);   off += 524288;
    f16*  h2b  = (f16*)(ws + off);
    const size_t fixed = off;

    long long availC = 0;
    if (ws_size > fixed) availC = (long long)((ws_size - fixed) / 512);   // 256 f16/edge
    int C = (availC > NEDGE) ? NEDGE : (int)availC;
    C &= ~255;                     // multiple of 256 (h2 block 64, msg block 128)
    if (C < 256) return;           // workspace too small: clean failure, no fault

    hipMemsetAsync(deg, 0, (size_t)NNODE * 4, stream);
    hipMemsetAsync(agg, 0, (size_t)NNODE * W32 * 4, stream);

    pack_k1<<<40, 256, 0, stream>>>(k1w, k1p);
    pack_k2<<<320, 256, 0, stream>>>(k2w, k2p);
    pack_k3<<<1024, 256, 0, stream>>>(k3w, k3r);

    h0_kernel<<<NNODE * W32 / 256, 256, 0, stream>>>(x, fc1w, fc1b, hA);
    deg_kernel<<<(NEDGE + 255) / 256, 256, 0, stream>>>(ei, deg);

    const bool full = (C == NEDGE);
    if (full)
        h2_kernel<<<NEDGE / 64, 256, 0, stream>>>(ea, k1p, k1b, k2p, k2b, h2b, 0);

    float* hcur = hA; float* hnext = hB;
    for (int d = 0; d < 4; ++d) {
        for (int es = 0; es < NEDGE; es += C) {
            int ce = (NEDGE - es < C) ? (NEDGE - es) : C;   // multiple of 256
            if (!full)
                h2_kernel<<<ce / 64, 256, 0, stream>>>(ea, k1p, k1b, k2p, k2b, h2b, es);
            msg_fused<<<ce / 128, 256, 0, stream>>>(ei, h2b, k3r, k3b, hcur, agg, es);
        }
        update_kernel<<<NNODE / 8, 256, 0, stream>>>(hcur, hnext, agg, deg, rootw, convb);
        float* tmp = hcur; hcur = hnext; hnext = tmp;
    }
    out_kernel<<<(NNODE + 255) / 256, 256, 0, stream>>>(hcur, fc2w, fc2b, out);
}

// Round 8
// 1215.534 us; speedup vs baseline: 2.2457x; 2.2457x over previous
//
#include <hip/hip_runtime.h>
#include <hip/hip_fp16.h>

#define NNODE 10000
#define NEDGE 160000
#define W32 32
#define BSTR 40          // f16 row stride for B panels (80 B, 16B-aligned)
#define PANEL_F16 10240  // h2 panels: 256 cols * 40
#define PANEL3_F16 5120  // msg panels: 128 cols * 40

typedef _Float16 f16;
typedef _Float16 f16x4 __attribute__((ext_vector_type(4)));
typedef _Float16 f16x8 __attribute__((ext_vector_type(8)));
typedef float f32x4 __attribute__((ext_vector_type(4)));

// ---- stage one 20480-B panel (1280 slots): wave w does slots [w*320, w*320+320) ----
__device__ __forceinline__ void stage_panel(f16* lds, const f16* g, int w, int lane) {
    #pragma unroll
    for (int i = 0; i < 5; ++i) {
        int slot = w * 320 + i * 64 + lane;
        __builtin_amdgcn_global_load_lds(
            (const __attribute__((address_space(1))) unsigned int*)(g + (size_t)slot * 8),
            (__attribute__((address_space(3))) unsigned int*)(lds + (size_t)(w * 320 + i * 64) * 8),
            16, 0, 0);
    }
}

// ---- stage one 10240-B panel (640 slots): 2 full passes + waves 0-1 half pass ----
__device__ __forceinline__ void stage_panel10k(f16* lds, const f16* g, int w, int lane) {
    #pragma unroll
    for (int i = 0; i < 2; ++i) {
        int base = i * 256 + w * 64;
        __builtin_amdgcn_global_load_lds(
            (const __attribute__((address_space(1))) unsigned int*)(g + (size_t)(base + lane) * 8),
            (__attribute__((address_space(3))) unsigned int*)(lds + (size_t)base * 8),
            16, 0, 0);
    }
    if (w < 2) {   // wave-uniform branch
        int base = 512 + w * 64;
        __builtin_amdgcn_global_load_lds(
            (const __attribute__((address_space(1))) unsigned int*)(g + (size_t)(base + lane) * 8),
            (__attribute__((address_space(3))) unsigned int*)(lds + (size_t)base * 8),
            16, 0, 0);
    }
}

// ================= weight packs (verified r4-r7) =================
__global__ __launch_bounds__(256) void pack_k1(const float* __restrict__ k1w, f16* __restrict__ k1p) {
    int t = blockIdx.x * 256 + threadIdx.x;           // 10240
    int j = t / BSTR, c = t % BSTR;
    k1p[t] = (c < 6) ? (f16)k1w[c * 256 + j] : (f16)0.f;
}
__global__ __launch_bounds__(256) void pack_k2(const float* __restrict__ k2w, f16* __restrict__ k2p) {
    int t = blockIdx.x * 256 + threadIdx.x;           // 8*10240
    int kk = t / PANEL_F16, r = t % PANEL_F16;
    int j = r / BSTR, c = r % BSTR;
    k2p[t] = (c < 32) ? (f16)k2w[(size_t)(kk * 32 + c) * 256 + j] : (f16)0.f;
}
// k3 panels of 128 cols: panel p = np*8+kk holds k3[kk*32+c][np*128+j] at r=j*40+c
__global__ __launch_bounds__(256) void pack_k3(const float* __restrict__ k3w, f16* __restrict__ k3p) {
    int t = blockIdx.x * 256 + threadIdx.x;           // 64*5120
    int p = t / PANEL3_F16, r = t % PANEL3_F16;
    int np = p >> 3, kk = p & 7;
    int j = r / BSTR, c = r % BSTR;
    k3p[t] = (c < 32) ? (f16)k3w[(size_t)(kk * 32 + c) * 1024 + np * 128 + j] : (f16)0.f;
}

// ================= h2 = relu(relu(ea@k1+b1)@k2+b2), fp16 out (verified r4-r6) =============
__global__ __launch_bounds__(256) void h2_kernel(
    const float* __restrict__ ea,
    const f16* __restrict__ k1p, const float* __restrict__ k1b,
    const f16* __restrict__ k2p, const float* __restrict__ k2b,
    f16* __restrict__ h2c, int e_start)
{
    __shared__ __align__(16) f16 bls[256 * BSTR];
    __shared__ __align__(16) f16 ea_s[64 * BSTR];
    __shared__ __align__(16) f16 hbuf[64 * 264];

    const int t = threadIdx.x, w = t >> 6, lane = t & 63, quad = lane >> 4, l15 = lane & 15;
    const int el0 = blockIdx.x * 64;
    const int e0 = e_start + el0;

    for (int i = t; i < 64 * BSTR; i += 256) {
        int e = i / BSTR, c = i % BSTR;
        ea_s[i] = (f16)((c < 6) ? ea[(size_t)(e0 + e) * 6 + c] : 0.f);
    }
    stage_panel(bls, k1p, w, lane);
    __syncthreads();

    f16x8 a1 = *(const f16x8*)&ea_s[(w * 16 + l15) * BSTR + quad * 8];
    f32x4 acc[16];
    #pragma unroll
    for (int nt = 0; nt < 16; ++nt) { float b = k1b[nt * 16 + l15]; acc[nt] = (f32x4){b, b, b, b}; }
    #pragma unroll
    for (int nt = 0; nt < 16; ++nt) {
        f16x8 bf = *(const f16x8*)&bls[(nt * 16 + l15) * BSTR + quad * 8];
        acc[nt] = __builtin_amdgcn_mfma_f32_16x16x32_f16(a1, bf, acc[nt], 0, 0, 0);
    }
    __syncthreads();
    #pragma unroll
    for (int nt = 0; nt < 16; ++nt)
        #pragma unroll
        for (int r = 0; r < 4; ++r)
            hbuf[(w * 16 + quad * 4 + r) * 264 + nt * 16 + l15] = (f16)fmaxf(acc[nt][r], 0.f);
    __syncthreads();

    f16x8 a2[8];
    #pragma unroll
    for (int kk = 0; kk < 8; ++kk)
        a2[kk] = *(const f16x8*)&hbuf[(w * 16 + l15) * 264 + kk * 32 + quad * 8];
    #pragma unroll
    for (int nt = 0; nt < 16; ++nt) { float b = k2b[nt * 16 + l15]; acc[nt] = (f32x4){b, b, b, b}; }
    for (int kk = 0; kk < 8; ++kk) {
        __syncthreads();
        stage_panel(bls, k2p + (size_t)kk * PANEL_F16, w, lane);
        __syncthreads();
        #pragma unroll
        for (int nt = 0; nt < 16; ++nt) {
            f16x8 bf = *(const f16x8*)&bls[(nt * 16 + l15) * BSTR + quad * 8];
            acc[nt] = __builtin_amdgcn_mfma_f32_16x16x32_f16(a2[kk], bf, acc[nt], 0, 0, 0);
        }
    }
    #pragma unroll
    for (int nt = 0; nt < 16; ++nt)
        #pragma unroll
        for (int r = 0; r < 4; ++r)
            h2c[(size_t)(el0 + w * 16 + quad * 4 + r) * 256 + nt * 16 + l15] = (f16)fmaxf(acc[nt][r], 0.f);
}

// ========== fused msg: 256 edges/block; wm = edge-half, wn = o-half; B via LDS panels =====
// wave w: wm=w>>1 owns edges [wm*128, wm*128+128) (8 M-tiles of 16);
//         wn=w&1 owns panel N-tiles nt = 2*nt'+wn (o = wn*16+l15) -> no cross-wave overlap.
__global__ __launch_bounds__(256, 2) void msg_fused(
    const int* __restrict__ ei, const f16* __restrict__ h2c,
    const f16* __restrict__ k3p, const float* __restrict__ k3b,
    const float* __restrict__ h, float* __restrict__ agg, int e_start)
{
    __shared__ __align__(16) f16 bls[2][PANEL3_F16];  // 20480 B double buffer
    __shared__ __align__(16) f16 h_s[256 * 36];       // 18432 B (stride 36, f16x4-aligned)
    __shared__ int dst_s[256];

    const int t = threadIdx.x, w = t >> 6, lane = t & 63, quad = lane >> 4, l15 = lane & 15;
    const int wm = w >> 1, wn = w & 1;
    const int el0 = blockIdx.x * 256;                 // chunk-local
    const int e0 = e_start + el0;                     // global

    dst_s[t] = ei[NEDGE + e0 + t];
    {   // gather h[src] as fp16: one thread per edge (verified r4 pattern)
        int srcn = ei[e0 + t];
        const float4* hr = (const float4*)(h + (size_t)srcn * 32);
        f16* dp = &h_s[t * 36];
        #pragma unroll
        for (int qq = 0; qq < 8; ++qq) {
            float4 v = hr[qq];
            dp[qq * 4 + 0] = (f16)v.x; dp[qq * 4 + 1] = (f16)v.y;
            dp[qq * 4 + 2] = (f16)v.z; dp[qq * 4 + 3] = (f16)v.w;
        }
    }
    stage_panel10k(bls[0], k3p, w, lane);             // panel 0 async

    float msg[8][4];                                  // [M-tile][row] for o = wn*16+l15
    #pragma unroll
    for (int m = 0; m < 8; ++m)
        #pragma unroll
        for (int r = 0; r < 4; ++r) msg[m][r] = 0.f;

    f32x4 acc[8][4];                                  // [M-tile][nt']
    __syncthreads();                                  // h_s/dst_s + panel 0 ready

    for (int it = 0; it < 64; ++it) {
        const int np = it >> 3, kk = it & 7;
        if (it) __syncthreads();                      // panel `it` ready; other buffer free
        if (it < 63) stage_panel10k(bls[(it + 1) & 1], k3p + (size_t)(it + 1) * PANEL3_F16, w, lane);

        if (kk == 0) {   // bias init: col = np*128 + (2*nt'+wn)*16 + l15
            #pragma unroll
            for (int nt = 0; nt < 4; ++nt) {
                float bv = k3b[np * 128 + (2 * nt + wn) * 16 + l15];
                #pragma unroll
                for (int m = 0; m < 8; ++m) acc[m][nt] = (f32x4){bv, bv, bv, bv};
            }
        }

        // B: this wave's 4 N-tiles (nt = 2*nt'+wn) from LDS
        const f16* B = bls[it & 1];
        f16x8 b[4];
        #pragma unroll
        for (int nt = 0; nt < 4; ++nt)
            b[nt] = *(const f16x8*)&B[((2 * nt + wn) * 16 + l15) * BSTR + quad * 8];

        // A: this wave's 128 edges from global h2c (L2-hot within block)
        const f16* abase = h2c + (size_t)(el0 + wm * 128) * 256 + kk * 32 + quad * 8;
        #pragma unroll
        for (int m = 0; m < 8; ++m) {
            f16x8 a = *(const f16x8*)(abase + (size_t)(m * 16 + l15) * 256);
            #pragma unroll
            for (int nt = 0; nt < 4; ++nt)
                acc[m][nt] = __builtin_amdgcn_mfma_f32_16x16x32_f16(a, b[nt], acc[m][nt], 0, 0, 0);
        }

        if (kk == 7) {   // fold np's W cols: i = np*4 + nt', o = wn*16 + l15 (r4-verified form)
            #pragma unroll
            for (int m = 0; m < 8; ++m)
                #pragma unroll
                for (int r = 0; r < 4; ++r) {
                    int row = wm * 128 + m * 16 + quad * 4 + r;
                    f16x4 h4 = *(const f16x4*)&h_s[row * 36 + np * 4];
                    #pragma unroll
                    for (int nt = 0; nt < 4; ++nt)
                        msg[m][r] += (float)h4[nt] * acc[m][nt][r];
                }
        }
    }

    // one atomic per (edge, o); each (edge,o) owned by exactly one wave
    #pragma unroll
    for (int m = 0; m < 8; ++m)
        #pragma unroll
        for (int r = 0; r < 4; ++r) {
            int row = wm * 128 + m * 16 + quad * 4 + r;
            atomicAdd(&agg[dst_s[row] * W32 + wn * 16 + l15], msg[m][r]);
        }
}

// ================= small kernels (verified) =================
__global__ __launch_bounds__(256) void h0_kernel(
    const float* __restrict__ x, const float* __restrict__ fc1w,
    const float* __restrict__ fc1b, float* __restrict__ h)
{
    int idx = blockIdx.x * 256 + threadIdx.x;
    int n = idx >> 5, j = idx & 31;
    h[idx] = x[n] * fc1w[j] + fc1b[j];
}

__global__ __launch_bounds__(256) void deg_kernel(
    const int* __restrict__ ei, float* __restrict__ deg)
{
    int e = blockIdx.x * 256 + threadIdx.x;
    if (e < NEDGE) atomicAdd(&deg[ei[NEDGE + e]], 1.f);
}

__global__ __launch_bounds__(256) void update_kernel(
    const float* __restrict__ h_old, float* __restrict__ h_new,
    float* __restrict__ agg, const float* __restrict__ deg,
    const float* __restrict__ rootw, const float* __restrict__ convb)
{
    __shared__ float rw[W32][W32 + 1];
    const int t = threadIdx.x;
    for (int q = t; q < W32 * W32; q += 256)
        rw[q >> 5][q & 31] = rootw[q];
    __syncthreads();
    const int nl = t >> 5, j = t & 31;
    const int n = blockIdx.x * 8 + nl;
    float hv = h_old[n * W32 + j];
    float acc = convb[j];
    #pragma unroll
    for (int k = 0; k < W32; ++k)
        acc += __shfl(hv, k, 32) * rw[k][j];
    float inv = 1.f / fmaxf(deg[n], 1.f);
    int idx = n * W32 + j;
    float a = agg[idx];
    agg[idx] = 0.f;
    h_new[idx] = fmaxf(a * inv + acc, 0.f);
}

__global__ __launch_bounds__(256) void out_kernel(
    const float* __restrict__ h, const float* __restrict__ fc2w,
    const float* __restrict__ fc2b, float* __restrict__ out)
{
    int n = blockIdx.x * 256 + threadIdx.x;
    if (n < NNODE) {
        float a = fc2b[0];
        #pragma unroll
        for (int j = 0; j < W32; ++j)
            a += h[n * W32 + j] * fc2w[j];
        out[n] = a;
    }
}

extern "C" void kernel_launch(void* const* d_in, const int* in_sizes, int n_in,
                              void* d_out, int out_size, void* d_ws, size_t ws_size,
                              hipStream_t stream) {
    const float* x    = (const float*)d_in[0];
    const int*   ei   = (const int*)  d_in[1];
    const float* ea   = (const float*)d_in[2];
    const float* fc1w = (const float*)d_in[3];
    const float* fc1b = (const float*)d_in[4];
    const float* k1w  = (const float*)d_in[5];
    const float* k1b  = (const float*)d_in[6];
    const float* k2w  = (const float*)d_in[7];
    const float* k2b  = (const float*)d_in[8];
    const float* k3w  = (const float*)d_in[9];
    const float* k3b  = (const float*)d_in[10];
    const float* rootw= (const float*)d_in[11];
    const float* convb= (const float*)d_in[12];
    const float* fc2w = (const float*)d_in[13];
    const float* fc2b = (const float*)d_in[14];
    float* out = (float*)d_out;

    const size_t hbytes = (size_t)NNODE * W32 * 4;
    char* ws = (char*)d_ws;
    size_t off = 0;
    float* hA  = (float*)(ws + off); off += hbytes;
    float* hB  = (float*)(ws + off); off += hbytes;
    float* agg = (float*)(ws + off); off += hbytes;
    float* deg = (float*)(ws + off); off += 40960;
    f16*  k1p  = (f16*)(ws + off);   off += 20480;
    f16*  k2p  = (f16*)(ws + off);   off += 163840;
    f16*  k3p  = (f16*)(ws + off);   off += 655360;
    f16*  h2b  = (f16*)(ws + off);
    const size_t fixed = off;

    long long availC = 0;
    if (ws_size > fixed) availC = (long long)((ws_size - fixed) / 512);   // 256 f16/edge
    int C = (availC > NEDGE) ? NEDGE : (int)availC;
    C &= ~255;                     // multiple of 256 (msg block) and 64 (h2 block)
    if (C < 256) return;           // workspace too small: clean failure, no fault

    hipMemsetAsync(deg, 0, (size_t)NNODE * 4, stream);
    hipMemsetAsync(agg, 0, (size_t)NNODE * W32 * 4, stream);

    pack_k1<<<40, 256, 0, stream>>>(k1w, k1p);
    pack_k2<<<320, 256, 0, stream>>>(k2w, k2p);
    pack_k3<<<1280, 256, 0, stream>>>(k3w, k3p);

    h0_kernel<<<NNODE * W32 / 256, 256, 0, stream>>>(x, fc1w, fc1b, hA);
    deg_kernel<<<(NEDGE + 255) / 256, 256, 0, stream>>>(ei, deg);

    const bool full = (C == NEDGE);
    if (full)
        h2_kernel<<<NEDGE / 64, 256, 0, stream>>>(ea, k1p, k1b, k2p, k2b, h2b, 0);

    float* hcur = hA; float* hnext = hB;
    for (int d = 0; d < 4; ++d) {
        for (int es = 0; es < NEDGE; es += C) {
            int ce = (NEDGE - es < C) ? (NEDGE - es) : C;   // multiple of 256
            if (!full)
                h2_kernel<<<ce / 64, 256, 0, stream>>>(ea, k1p, k1b, k2p, k2b, h2b, es);
            msg_fused<<<ce / 256, 256, 0, stream>>>(ei, h2b, k3p, k3b, hcur, agg, es);
        }
        update_kernel<<<NNODE / 8, 256, 0, stream>>>(hcur, hnext, agg, deg, rootw, convb);
        float* tmp = hcur; hcur = hnext; hnext = tmp;
    }
    out_kernel<<<(NNODE + 255) / 256, 256, 0, stream>>>(hcur, fc2w, fc2b, out);
}

// Round 9
// 1118.825 us; speedup vs baseline: 2.4398x; 1.0864x over previous
//
#include <hip/hip_runtime.h>
#include <hip/hip_fp16.h>

#define NNODE 10000
#define NEDGE 160000
#define W32 32
#define BSTR 40          // f16 row stride for B panels (80 B, 16B-aligned)
#define PANEL_F16 10240  // h2 panels: 256 cols * 40
#define PANEL3_F16 5120  // msg panels: 128 cols * 40

typedef _Float16 f16;
typedef _Float16 f16x4 __attribute__((ext_vector_type(4)));
typedef _Float16 f16x8 __attribute__((ext_vector_type(8)));
typedef float f32x4 __attribute__((ext_vector_type(4)));

// ---- stage one 20480-B panel (1280 slots): wave w does slots [w*320, w*320+320) ----
__device__ __forceinline__ void stage_panel(f16* lds, const f16* g, int w, int lane) {
    #pragma unroll
    for (int i = 0; i < 5; ++i) {
        int slot = w * 320 + i * 64 + lane;
        __builtin_amdgcn_global_load_lds(
            (const __attribute__((address_space(1))) unsigned int*)(g + (size_t)slot * 8),
            (__attribute__((address_space(3))) unsigned int*)(lds + (size_t)(w * 320 + i * 64) * 8),
            16, 0, 0);
    }
}

// ---- stage one 10240-B panel (640 slots): 2 full passes + waves 0-1 half pass ----
__device__ __forceinline__ void stage_panel10k(f16* lds, const f16* g, int w, int lane) {
    #pragma unroll
    for (int i = 0; i < 2; ++i) {
        int base = i * 256 + w * 64;
        __builtin_amdgcn_global_load_lds(
            (const __attribute__((address_space(1))) unsigned int*)(g + (size_t)(base + lane) * 8),
            (__attribute__((address_space(3))) unsigned int*)(lds + (size_t)base * 8),
            16, 0, 0);
    }
    if (w < 2) {   // wave-uniform branch
        int base = 512 + w * 64;
        __builtin_amdgcn_global_load_lds(
            (const __attribute__((address_space(1))) unsigned int*)(g + (size_t)(base + lane) * 8),
            (__attribute__((address_space(3))) unsigned int*)(lds + (size_t)base * 8),
            16, 0, 0);
    }
}

// ================= weight packs (verified r4-r8) =================
__global__ __launch_bounds__(256) void pack_k1(const float* __restrict__ k1w, f16* __restrict__ k1p) {
    int t = blockIdx.x * 256 + threadIdx.x;           // 10240
    int j = t / BSTR, c = t % BSTR;
    k1p[t] = (c < 6) ? (f16)k1w[c * 256 + j] : (f16)0.f;
}
__global__ __launch_bounds__(256) void pack_k2(const float* __restrict__ k2w, f16* __restrict__ k2p) {
    int t = blockIdx.x * 256 + threadIdx.x;           // 8*10240
    int kk = t / PANEL_F16, r = t % PANEL_F16;
    int j = r / BSTR, c = r % BSTR;
    k2p[t] = (c < 32) ? (f16)k2w[(size_t)(kk * 32 + c) * 256 + j] : (f16)0.f;
}
// k3 panels of 128 cols: panel p = np*8+kk holds k3[kk*32+c][np*128+j] at r=j*40+c
__global__ __launch_bounds__(256) void pack_k3(const float* __restrict__ k3w, f16* __restrict__ k3p) {
    int t = blockIdx.x * 256 + threadIdx.x;           // 64*5120
    int p = t / PANEL3_F16, r = t % PANEL3_F16;
    int np = p >> 3, kk = p & 7;
    int j = r / BSTR, c = r % BSTR;
    k3p[t] = (c < 32) ? (f16)k3w[(size_t)(kk * 32 + c) * 1024 + np * 128 + j] : (f16)0.f;
}

// ================= h2 = relu(relu(ea@k1+b1)@k2+b2), fp16 out (verified r4-r8) =============
__global__ __launch_bounds__(256) void h2_kernel(
    const float* __restrict__ ea,
    const f16* __restrict__ k1p, const float* __restrict__ k1b,
    const f16* __restrict__ k2p, const float* __restrict__ k2b,
    f16* __restrict__ h2c, int e_start)
{
    __shared__ __align__(16) f16 bls[256 * BSTR];
    __shared__ __align__(16) f16 ea_s[64 * BSTR];
    __shared__ __align__(16) f16 hbuf[64 * 264];

    const int t = threadIdx.x, w = t >> 6, lane = t & 63, quad = lane >> 4, l15 = lane & 15;
    const int el0 = blockIdx.x * 64;
    const int e0 = e_start + el0;

    for (int i = t; i < 64 * BSTR; i += 256) {
        int e = i / BSTR, c = i % BSTR;
        ea_s[i] = (f16)((c < 6) ? ea[(size_t)(e0 + e) * 6 + c] : 0.f);
    }
    stage_panel(bls, k1p, w, lane);
    __syncthreads();

    f16x8 a1 = *(const f16x8*)&ea_s[(w * 16 + l15) * BSTR + quad * 8];
    f32x4 acc[16];
    #pragma unroll
    for (int nt = 0; nt < 16; ++nt) { float b = k1b[nt * 16 + l15]; acc[nt] = (f32x4){b, b, b, b}; }
    #pragma unroll
    for (int nt = 0; nt < 16; ++nt) {
        f16x8 bf = *(const f16x8*)&bls[(nt * 16 + l15) * BSTR + quad * 8];
        acc[nt] = __builtin_amdgcn_mfma_f32_16x16x32_f16(a1, bf, acc[nt], 0, 0, 0);
    }
    __syncthreads();
    #pragma unroll
    for (int nt = 0; nt < 16; ++nt)
        #pragma unroll
        for (int r = 0; r < 4; ++r)
            hbuf[(w * 16 + quad * 4 + r) * 264 + nt * 16 + l15] = (f16)fmaxf(acc[nt][r], 0.f);
    __syncthreads();

    f16x8 a2[8];
    #pragma unroll
    for (int kk = 0; kk < 8; ++kk)
        a2[kk] = *(const f16x8*)&hbuf[(w * 16 + l15) * 264 + kk * 32 + quad * 8];
    #pragma unroll
    for (int nt = 0; nt < 16; ++nt) { float b = k2b[nt * 16 + l15]; acc[nt] = (f32x4){b, b, b, b}; }
    for (int kk = 0; kk < 8; ++kk) {
        __syncthreads();
        stage_panel(bls, k2p + (size_t)kk * PANEL_F16, w, lane);
        __syncthreads();
        #pragma unroll
        for (int nt = 0; nt < 16; ++nt) {
            f16x8 bf = *(const f16x8*)&bls[(nt * 16 + l15) * BSTR + quad * 8];
            acc[nt] = __builtin_amdgcn_mfma_f32_16x16x32_f16(a2[kk], bf, acc[nt], 0, 0, 0);
        }
    }
    #pragma unroll
    for (int nt = 0; nt < 16; ++nt)
        #pragma unroll
        for (int r = 0; r < 4; ++r)
            h2c[(size_t)(el0 + w * 16 + quad * 4 + r) * 256 + nt * 16 + l15] = (f16)fmaxf(acc[nt][r], 0.f);
}

// ========== fused msg v6: 128 edges/block; wm = edge-half (64 edges), wn = o-half ==========
// Identical index mapping to r8 (verified), with wm stride 128->64 and smaller tiles:
// acc[4][4] (64 AGPR), msg[4][4] -> ~150 reg/wave -> 3 waves/SIMD, 3 blocks/CU.
__global__ __launch_bounds__(256, 3) void msg_fused(
    const int* __restrict__ ei, const f16* __restrict__ h2c,
    const f16* __restrict__ k3p, const float* __restrict__ k3b,
    const float* __restrict__ h, float* __restrict__ agg, int e_start)
{
    __shared__ __align__(16) f16 bls[2][PANEL3_F16];  // 20480 B double buffer
    __shared__ __align__(16) f16 h_s[128 * 36];       // 9216 B (stride 36, f16x4-aligned)
    __shared__ int dst_s[128];

    const int t = threadIdx.x, w = t >> 6, lane = t & 63, quad = lane >> 4, l15 = lane & 15;
    const int wm = w >> 1, wn = w & 1;
    const int el0 = blockIdx.x * 128;                 // chunk-local
    const int e0 = e_start + el0;                     // global

    if (t < 128) {   // gather dst + h[src] as fp16: one thread per edge (r8 pattern)
        dst_s[t] = ei[NEDGE + e0 + t];
        int srcn = ei[e0 + t];
        const float4* hr = (const float4*)(h + (size_t)srcn * 32);
        f16* dp = &h_s[t * 36];
        #pragma unroll
        for (int qq = 0; qq < 8; ++qq) {
            float4 v = hr[qq];
            dp[qq * 4 + 0] = (f16)v.x; dp[qq * 4 + 1] = (f16)v.y;
            dp[qq * 4 + 2] = (f16)v.z; dp[qq * 4 + 3] = (f16)v.w;
        }
    }
    stage_panel10k(bls[0], k3p, w, lane);             // panel 0 async

    float msg[4][4];                                  // [M-tile][row] for o = wn*16+l15
    #pragma unroll
    for (int m = 0; m < 4; ++m)
        #pragma unroll
        for (int r = 0; r < 4; ++r) msg[m][r] = 0.f;

    f32x4 acc[4][4];                                  // [M-tile][nt']
    __syncthreads();                                  // h_s/dst_s + panel 0 ready

    for (int it = 0; it < 64; ++it) {
        const int np = it >> 3, kk = it & 7;
        if (it) __syncthreads();                      // panel `it` ready; other buffer free
        if (it < 63) stage_panel10k(bls[(it + 1) & 1], k3p + (size_t)(it + 1) * PANEL3_F16, w, lane);

        if (kk == 0) {   // bias init: col = np*128 + (2*nt'+wn)*16 + l15
            #pragma unroll
            for (int nt = 0; nt < 4; ++nt) {
                float bv = k3b[np * 128 + (2 * nt + wn) * 16 + l15];
                #pragma unroll
                for (int m = 0; m < 4; ++m) acc[m][nt] = (f32x4){bv, bv, bv, bv};
            }
        }

        // B: this wave's 4 N-tiles (nt = 2*nt'+wn) from LDS
        const f16* B = bls[it & 1];
        f16x8 b[4];
        #pragma unroll
        for (int nt = 0; nt < 4; ++nt)
            b[nt] = *(const f16x8*)&B[((2 * nt + wn) * 16 + l15) * BSTR + quad * 8];

        // A: this wave's 64 edges from global h2c (L2-hot within block)
        const f16* abase = h2c + (size_t)(el0 + wm * 64) * 256 + kk * 32 + quad * 8;
        #pragma unroll
        for (int m = 0; m < 4; ++m) {
            f16x8 a = *(const f16x8*)(abase + (size_t)(m * 16 + l15) * 256);
            #pragma unroll
            for (int nt = 0; nt < 4; ++nt)
                acc[m][nt] = __builtin_amdgcn_mfma_f32_16x16x32_f16(a, b[nt], acc[m][nt], 0, 0, 0);
        }

        if (kk == 7) {   // fold np's W cols: i = np*4 + nt', o = wn*16 + l15 (r8-verified)
            #pragma unroll
            for (int m = 0; m < 4; ++m)
                #pragma unroll
                for (int r = 0; r < 4; ++r) {
                    int row = wm * 64 + m * 16 + quad * 4 + r;
                    f16x4 h4 = *(const f16x4*)&h_s[row * 36 + np * 4];
                    #pragma unroll
                    for (int nt = 0; nt < 4; ++nt)
                        msg[m][r] += (float)h4[nt] * acc[m][nt][r];
                }
        }
    }

    // one atomic per (edge, o); each (edge,o) owned by exactly one wave
    #pragma unroll
    for (int m = 0; m < 4; ++m)
        #pragma unroll
        for (int r = 0; r < 4; ++r) {
            int row = wm * 64 + m * 16 + quad * 4 + r;
            atomicAdd(&agg[dst_s[row] * W32 + wn * 16 + l15], msg[m][r]);
        }
}

// ================= small kernels (verified) =================
__global__ __launch_bounds__(256) void h0_kernel(
    const float* __restrict__ x, const float* __restrict__ fc1w,
    const float* __restrict__ fc1b, float* __restrict__ h)
{
    int idx = blockIdx.x * 256 + threadIdx.x;
    int n = idx >> 5, j = idx & 31;
    h[idx] = x[n] * fc1w[j] + fc1b[j];
}

__global__ __launch_bounds__(256) void deg_kernel(
    const int* __restrict__ ei, float* __restrict__ deg)
{
    int e = blockIdx.x * 256 + threadIdx.x;
    if (e < NEDGE) atomicAdd(&deg[ei[NEDGE + e]], 1.f);
}

__global__ __launch_bounds__(256) void update_kernel(
    const float* __restrict__ h_old, float* __restrict__ h_new,
    float* __restrict__ agg, const float* __restrict__ deg,
    const float* __restrict__ rootw, const float* __restrict__ convb)
{
    __shared__ float rw[W32][W32 + 1];
    const int t = threadIdx.x;
    for (int q = t; q < W32 * W32; q += 256)
        rw[q >> 5][q & 31] = rootw[q];
    __syncthreads();
    const int nl = t >> 5, j = t & 31;
    const int n = blockIdx.x * 8 + nl;
    float hv = h_old[n * W32 + j];
    float acc = convb[j];
    #pragma unroll
    for (int k = 0; k < W32; ++k)
        acc += __shfl(hv, k, 32) * rw[k][j];
    float inv = 1.f / fmaxf(deg[n], 1.f);
    int idx = n * W32 + j;
    float a = agg[idx];
    agg[idx] = 0.f;
    h_new[idx] = fmaxf(a * inv + acc, 0.f);
}

__global__ __launch_bounds__(256) void out_kernel(
    const float* __restrict__ h, const float* __restrict__ fc2w,
    const float* __restrict__ fc2b, float* __restrict__ out)
{
    int n = blockIdx.x * 256 + threadIdx.x;
    if (n < NNODE) {
        float a = fc2b[0];
        #pragma unroll
        for (int j = 0; j < W32; ++j)
            a += h[n * W32 + j] * fc2w[j];
        out[n] = a;
    }
}

extern "C" void kernel_launch(void* const* d_in, const int* in_sizes, int n_in,
                              void* d_out, int out_size, void* d_ws, size_t ws_size,
                              hipStream_t stream) {
    const float* x    = (const float*)d_in[0];
    const int*   ei   = (const int*)  d_in[1];
    const float* ea   = (const float*)d_in[2];
    const float* fc1w = (const float*)d_in[3];
    const float* fc1b = (const float*)d_in[4];
    const float* k1w  = (const float*)d_in[5];
    const float* k1b  = (const float*)d_in[6];
    const float* k2w  = (const float*)d_in[7];
    const float* k2b  = (const float*)d_in[8];
    const float* k3w  = (const float*)d_in[9];
    const float* k3b  = (const float*)d_in[10];
    const float* rootw= (const float*)d_in[11];
    const float* convb= (const float*)d_in[12];
    const float* fc2w = (const float*)d_in[13];
    const float* fc2b = (const float*)d_in[14];
    float* out = (float*)d_out;

    const size_t hbytes = (size_t)NNODE * W32 * 4;
    char* ws = (char*)d_ws;
    size_t off = 0;
    float* hA  = (float*)(ws + off); off += hbytes;
    float* hB  = (float*)(ws + off); off += hbytes;
    float* agg = (float*)(ws + off); off += hbytes;
    float* deg = (float*)(ws + off); off += 40960;
    f16*  k1p  = (f16*)(ws + off);   off += 20480;
    f16*  k2p  = (f16*)(ws + off);   off += 163840;
    f16*  k3p  = (f16*)(ws + off);   off += 655360;
    f16*  h2b  = (f16*)(ws + off);
    const size_t fixed = off;

    long long availC = 0;
    if (ws_size > fixed) availC = (long long)((ws_size - fixed) / 512);   // 256 f16/edge
    int C = (availC > NEDGE) ? NEDGE : (int)availC;
    C &= ~127;                     // multiple of 128 (msg block) and 64 (h2 block)
    if (C < 128) return;           // workspace too small: clean failure, no fault

    hipMemsetAsync(deg, 0, (size_t)NNODE * 4, stream);
    hipMemsetAsync(agg, 0, (size_t)NNODE * W32 * 4, stream);

    pack_k1<<<40, 256, 0, stream>>>(k1w, k1p);
    pack_k2<<<320, 256, 0, stream>>>(k2w, k2p);
    pack_k3<<<1280, 256, 0, stream>>>(k3w, k3p);

    h0_kernel<<<NNODE * W32 / 256, 256, 0, stream>>>(x, fc1w, fc1b, hA);
    deg_kernel<<<(NEDGE + 255) / 256, 256, 0, stream>>>(ei, deg);

    const bool full = (C == NEDGE);
    if (full)
        h2_kernel<<<NEDGE / 64, 256, 0, stream>>>(ea, k1p, k1b, k2p, k2b, h2b, 0);

    float* hcur = hA; float* hnext = hB;
    for (int d = 0; d < 4; ++d) {
        for (int es = 0; es < NEDGE; es += C) {
            int ce = (NEDGE - es < C) ? (NEDGE - es) : C;   // multiple of 128
            if (!full)
                h2_kernel<<<ce / 64, 256, 0, stream>>>(ea, k1p, k1b, k2p, k2b, h2b, es);
            msg_fused<<<ce / 128, 256, 0, stream>>>(ei, h2b, k3p, k3b, hcur, agg, es);
        }
        update_kernel<<<NNODE / 8, 256, 0, stream>>>(hcur, hnext, agg, deg, rootw, convb);
        float* tmp = hcur; hcur = hnext; hnext = tmp;
    }
    out_kernel<<<(NNODE + 255) / 256, 256, 0, stream>>>(hcur, fc2w, fc2b, out);
}

// Round 10
// 935.278 us; speedup vs baseline: 2.9186x; 1.1962x over previous
//
#include <hip/hip_runtime.h>
#include <hip/hip_fp16.h>

#define NNODE 10000
#define NEDGE 160000
#define W32 32
#define BSTR 40          // f16 row stride for B panels (80 B, 16B-aligned)
#define PANEL_F16 10240  // h2 panels: 256 cols * 40
#define PANEL3_F16 5120  // msg panels: 128 cols * 40

typedef _Float16 f16;
typedef _Float16 f16x4 __attribute__((ext_vector_type(4)));
typedef _Float16 f16x8 __attribute__((ext_vector_type(8)));
typedef float f32x4 __attribute__((ext_vector_type(4)));

// ---- stage one 20480-B panel (1280 slots): wave w does slots [w*320, w*320+320) ----
__device__ __forceinline__ void stage_panel(f16* lds, const f16* g, int w, int lane) {
    #pragma unroll
    for (int i = 0; i < 5; ++i) {
        int slot = w * 320 + i * 64 + lane;
        __builtin_amdgcn_global_load_lds(
            (const __attribute__((address_space(1))) unsigned int*)(g + (size_t)slot * 8),
            (__attribute__((address_space(3))) unsigned int*)(lds + (size_t)(w * 320 + i * 64) * 8),
            16, 0, 0);
    }
}

// ---- stage one 10240-B panel (640 slots): 2 full passes + waves 0-1 half pass ----
__device__ __forceinline__ void stage_panel10k(f16* lds, const f16* g, int w, int lane) {
    #pragma unroll
    for (int i = 0; i < 2; ++i) {
        int base = i * 256 + w * 64;
        __builtin_amdgcn_global_load_lds(
            (const __attribute__((address_space(1))) unsigned int*)(g + (size_t)(base + lane) * 8),
            (__attribute__((address_space(3))) unsigned int*)(lds + (size_t)base * 8),
            16, 0, 0);
    }
    if (w < 2) {   // wave-uniform branch
        int base = 512 + w * 64;
        __builtin_amdgcn_global_load_lds(
            (const __attribute__((address_space(1))) unsigned int*)(g + (size_t)(base + lane) * 8),
            (__attribute__((address_space(3))) unsigned int*)(lds + (size_t)base * 8),
            16, 0, 0);
    }
}

// ================= weight packs (verified r4-r9) =================
__global__ __launch_bounds__(256) void pack_k1(const float* __restrict__ k1w, f16* __restrict__ k1p) {
    int t = blockIdx.x * 256 + threadIdx.x;           // 10240
    int j = t / BSTR, c = t % BSTR;
    k1p[t] = (c < 6) ? (f16)k1w[c * 256 + j] : (f16)0.f;
}
__global__ __launch_bounds__(256) void pack_k2(const float* __restrict__ k2w, f16* __restrict__ k2p) {
    int t = blockIdx.x * 256 + threadIdx.x;           // 8*10240
    int kk = t / PANEL_F16, r = t % PANEL_F16;
    int j = r / BSTR, c = r % BSTR;
    k2p[t] = (c < 32) ? (f16)k2w[(size_t)(kk * 32 + c) * 256 + j] : (f16)0.f;
}
// k3 panels of 128 cols: panel p = np*8+kk holds k3[kk*32+c][np*128+j] at r=j*40+c
__global__ __launch_bounds__(256) void pack_k3(const float* __restrict__ k3w, f16* __restrict__ k3p) {
    int t = blockIdx.x * 256 + threadIdx.x;           // 64*5120
    int p = t / PANEL3_F16, r = t % PANEL3_F16;
    int np = p >> 3, kk = p & 7;
    int j = r / BSTR, c = r % BSTR;
    k3p[t] = (c < 32) ? (f16)k3w[(size_t)(kk * 32 + c) * 1024 + np * 128 + j] : (f16)0.f;
}

// ================= h2 = relu(relu(ea@k1+b1)@k2+b2), fp16 out (verified r4-r9) =============
__global__ __launch_bounds__(256) void h2_kernel(
    const float* __restrict__ ea,
    const f16* __restrict__ k1p, const float* __restrict__ k1b,
    const f16* __restrict__ k2p, const float* __restrict__ k2b,
    f16* __restrict__ h2c, int e_start)
{
    __shared__ __align__(16) f16 bls[256 * BSTR];
    __shared__ __align__(16) f16 ea_s[64 * BSTR];
    __shared__ __align__(16) f16 hbuf[64 * 264];

    const int t = threadIdx.x, w = t >> 6, lane = t & 63, quad = lane >> 4, l15 = lane & 15;
    const int el0 = blockIdx.x * 64;
    const int e0 = e_start + el0;

    for (int i = t; i < 64 * BSTR; i += 256) {
        int e = i / BSTR, c = i % BSTR;
        ea_s[i] = (f16)((c < 6) ? ea[(size_t)(e0 + e) * 6 + c] : 0.f);
    }
    stage_panel(bls, k1p, w, lane);
    __syncthreads();

    f16x8 a1 = *(const f16x8*)&ea_s[(w * 16 + l15) * BSTR + quad * 8];
    f32x4 acc[16];
    #pragma unroll
    for (int nt = 0; nt < 16; ++nt) { float b = k1b[nt * 16 + l15]; acc[nt] = (f32x4){b, b, b, b}; }
    #pragma unroll
    for (int nt = 0; nt < 16; ++nt) {
        f16x8 bf = *(const f16x8*)&bls[(nt * 16 + l15) * BSTR + quad * 8];
        acc[nt] = __builtin_amdgcn_mfma_f32_16x16x32_f16(a1, bf, acc[nt], 0, 0, 0);
    }
    __syncthreads();
    #pragma unroll
    for (int nt = 0; nt < 16; ++nt)
        #pragma unroll
        for (int r = 0; r < 4; ++r)
            hbuf[(w * 16 + quad * 4 + r) * 264 + nt * 16 + l15] = (f16)fmaxf(acc[nt][r], 0.f);
    __syncthreads();

    f16x8 a2[8];
    #pragma unroll
    for (int kk = 0; kk < 8; ++kk)
        a2[kk] = *(const f16x8*)&hbuf[(w * 16 + l15) * 264 + kk * 32 + quad * 8];
    #pragma unroll
    for (int nt = 0; nt < 16; ++nt) { float b = k2b[nt * 16 + l15]; acc[nt] = (f32x4){b, b, b, b}; }
    for (int kk = 0; kk < 8; ++kk) {
        __syncthreads();
        stage_panel(bls, k2p + (size_t)kk * PANEL_F16, w, lane);
        __syncthreads();
        #pragma unroll
        for (int nt = 0; nt < 16; ++nt) {
            f16x8 bf = *(const f16x8*)&bls[(nt * 16 + l15) * BSTR + quad * 8];
            acc[nt] = __builtin_amdgcn_mfma_f32_16x16x32_f16(a2[kk], bf, acc[nt], 0, 0, 0);
        }
    }
    #pragma unroll
    for (int nt = 0; nt < 16; ++nt)
        #pragma unroll
        for (int r = 0; r < 4; ++r)
            h2c[(size_t)(el0 + w * 16 + quad * 4 + r) * 256 + nt * 16 + l15] = (f16)fmaxf(acc[nt][r], 0.f);
}

// ========== fused msg v7: r9 structure + software-pipelined A fragments ==========
// 128 edges/block; wm=w>>1 owns edges [wm*64, wm*64+64), wn=w&1 owns o-half (r8/r9-verified
// mapping). A(it+1) loads issued before MFMA(it) -> global latency hidden across one iter.
__global__ __launch_bounds__(256, 3) void msg_fused(
    const int* __restrict__ ei, const f16* __restrict__ h2c,
    const f16* __restrict__ k3p, const float* __restrict__ k3b,
    const float* __restrict__ h, float* __restrict__ agg, int e_start)
{
    __shared__ __align__(16) f16 bls[2][PANEL3_F16];  // 20480 B double buffer
    __shared__ __align__(16) f16 h_s[128 * 36];       // 9216 B (stride 36, f16x4-aligned)
    __shared__ int dst_s[128];

    const int t = threadIdx.x, w = t >> 6, lane = t & 63, quad = lane >> 4, l15 = lane & 15;
    const int wm = w >> 1, wn = w & 1;
    const int el0 = blockIdx.x * 128;                 // chunk-local
    const int e0 = e_start + el0;                     // global

    if (t < 128) {   // gather dst + h[src] as fp16: one thread per edge (r9 pattern)
        dst_s[t] = ei[NEDGE + e0 + t];
        int srcn = ei[e0 + t];
        const float4* hr = (const float4*)(h + (size_t)srcn * 32);
        f16* dp = &h_s[t * 36];
        #pragma unroll
        for (int qq = 0; qq < 8; ++qq) {
            float4 v = hr[qq];
            dp[qq * 4 + 0] = (f16)v.x; dp[qq * 4 + 1] = (f16)v.y;
            dp[qq * 4 + 2] = (f16)v.z; dp[qq * 4 + 3] = (f16)v.w;
        }
    }
    stage_panel10k(bls[0], k3p, w, lane);             // panel 0 async

    // A-fragment base for this wave's 64 edges
    const f16* const aRow = h2c + (size_t)(el0 + wm * 64) * 256 + quad * 8;

    // prologue: issue A loads for it=0 (kk=0)
    f16x8 a_cur[4], a_nxt[4];
    #pragma unroll
    for (int m = 0; m < 4; ++m)
        a_cur[m] = *(const f16x8*)(aRow + (size_t)(m * 16 + l15) * 256);

    float msg[4][4];                                  // [M-tile][row] for o = wn*16+l15
    #pragma unroll
    for (int m = 0; m < 4; ++m)
        #pragma unroll
        for (int r = 0; r < 4; ++r) msg[m][r] = 0.f;

    f32x4 acc[4][4];                                  // [M-tile][nt']
    __syncthreads();                                  // h_s/dst_s + panel 0 ready

    for (int it = 0; it < 64; ++it) {
        const int np = it >> 3, kk = it & 7;
        if (it) __syncthreads();                      // panel `it` ready; other buffer free
        if (it < 63) {
            stage_panel10k(bls[(it + 1) & 1], k3p + (size_t)(it + 1) * PANEL3_F16, w, lane);
            // prefetch A for it+1 (kk of it+1) -- consumed next iteration
            const int kk1 = (it + 1) & 7;
            #pragma unroll
            for (int m = 0; m < 4; ++m)
                a_nxt[m] = *(const f16x8*)(aRow + (size_t)(m * 16 + l15) * 256 + kk1 * 32);
        }

        if (kk == 0) {   // bias init: col = np*128 + (2*nt'+wn)*16 + l15
            #pragma unroll
            for (int nt = 0; nt < 4; ++nt) {
                float bv = k3b[np * 128 + (2 * nt + wn) * 16 + l15];
                #pragma unroll
                for (int m = 0; m < 4; ++m) acc[m][nt] = (f32x4){bv, bv, bv, bv};
            }
        }

        // B: this wave's 4 N-tiles (nt = 2*nt'+wn) from LDS
        const f16* B = bls[it & 1];
        f16x8 b[4];
        #pragma unroll
        for (int nt = 0; nt < 4; ++nt)
            b[nt] = *(const f16x8*)&B[((2 * nt + wn) * 16 + l15) * BSTR + quad * 8];

        // MFMA with A loaded one iteration ago (latency hidden)
        #pragma unroll
        for (int m = 0; m < 4; ++m)
            #pragma unroll
            for (int nt = 0; nt < 4; ++nt)
                acc[m][nt] = __builtin_amdgcn_mfma_f32_16x16x32_f16(a_cur[m], b[nt], acc[m][nt], 0, 0, 0);

        if (kk == 7) {   // fold np's W cols: i = np*4 + nt', o = wn*16 + l15 (r9-verified)
            #pragma unroll
            for (int m = 0; m < 4; ++m)
                #pragma unroll
                for (int r = 0; r < 4; ++r) {
                    int row = wm * 64 + m * 16 + quad * 4 + r;
                    f16x4 h4 = *(const f16x4*)&h_s[row * 36 + np * 4];
                    #pragma unroll
                    for (int nt = 0; nt < 4; ++nt)
                        msg[m][r] += (float)h4[nt] * acc[m][nt][r];
                }
        }

        #pragma unroll
        for (int m = 0; m < 4; ++m) a_cur[m] = a_nxt[m];   // ping-pong
    }

    // one atomic per (edge, o); each (edge,o) owned by exactly one wave
    #pragma unroll
    for (int m = 0; m < 4; ++m)
        #pragma unroll
        for (int r = 0; r < 4; ++r) {
            int row = wm * 64 + m * 16 + quad * 4 + r;
            atomicAdd(&agg[dst_s[row] * W32 + wn * 16 + l15], msg[m][r]);
        }
}

// ================= small kernels (verified) =================
__global__ __launch_bounds__(256) void h0_kernel(
    const float* __restrict__ x, const float* __restrict__ fc1w,
    const float* __restrict__ fc1b, float* __restrict__ h)
{
    int idx = blockIdx.x * 256 + threadIdx.x;
    int n = idx >> 5, j = idx & 31;
    h[idx] = x[n] * fc1w[j] + fc1b[j];
}

__global__ __launch_bounds__(256) void deg_kernel(
    const int* __restrict__ ei, float* __restrict__ deg)
{
    int e = blockIdx.x * 256 + threadIdx.x;
    if (e < NEDGE) atomicAdd(&deg[ei[NEDGE + e]], 1.f);
}

__global__ __launch_bounds__(256) void update_kernel(
    const float* __restrict__ h_old, float* __restrict__ h_new,
    float* __restrict__ agg, const float* __restrict__ deg,
    const float* __restrict__ rootw, const float* __restrict__ convb)
{
    __shared__ float rw[W32][W32 + 1];
    const int t = threadIdx.x;
    for (int q = t; q < W32 * W32; q += 256)
        rw[q >> 5][q & 31] = rootw[q];
    __syncthreads();
    const int nl = t >> 5, j = t & 31;
    const int n = blockIdx.x * 8 + nl;
    float hv = h_old[n * W32 + j];
    float acc = convb[j];
    #pragma unroll
    for (int k = 0; k < W32; ++k)
        acc += __shfl(hv, k, 32) * rw[k][j];
    float inv = 1.f / fmaxf(deg[n], 1.f);
    int idx = n * W32 + j;
    float a = agg[idx];
    agg[idx] = 0.f;
    h_new[idx] = fmaxf(a * inv + acc, 0.f);
}

__global__ __launch_bounds__(256) void out_kernel(
    const float* __restrict__ h, const float* __restrict__ fc2w,
    const float* __restrict__ fc2b, float* __restrict__ out)
{
    int n = blockIdx.x * 256 + threadIdx.x;
    if (n < NNODE) {
        float a = fc2b[0];
        #pragma unroll
        for (int j = 0; j < W32; ++j)
            a += h[n * W32 + j] * fc2w[j];
        out[n] = a;
    }
}

extern "C" void kernel_launch(void* const* d_in, const int* in_sizes, int n_in,
                              void* d_out, int out_size, void* d_ws, size_t ws_size,
                              hipStream_t stream) {
    const float* x    = (const float*)d_in[0];
    const int*   ei   = (const int*)  d_in[1];
    const float* ea   = (const float*)d_in[2];
    const float* fc1w = (const float*)d_in[3];
    const float* fc1b = (const float*)d_in[4];
    const float* k1w  = (const float*)d_in[5];
    const float* k1b  = (const float*)d_in[6];
    const float* k2w  = (const float*)d_in[7];
    const float* k2b  = (const float*)d_in[8];
    const float* k3w  = (const float*)d_in[9];
    const float* k3b  = (const float*)d_in[10];
    const float* rootw= (const float*)d_in[11];
    const float* convb= (const float*)d_in[12];
    const float* fc2w = (const float*)d_in[13];
    const float* fc2b = (const float*)d_in[14];
    float* out = (float*)d_out;

    const size_t hbytes = (size_t)NNODE * W32 * 4;
    char* ws = (char*)d_ws;
    size_t off = 0;
    float* hA  = (float*)(ws + off); off += hbytes;
    float* hB  = (float*)(ws + off); off += hbytes;
    float* agg = (float*)(ws + off); off += hbytes;
    float* deg = (float*)(ws + off); off += 40960;
    f16*  k1p  = (f16*)(ws + off);   off += 20480;
    f16*  k2p  = (f16*)(ws + off);   off += 163840;
    f16*  k3p  = (f16*)(ws + off);   off += 655360;
    f16*  h2b  = (f16*)(ws + off);
    const size_t fixed = off;

    long long availC = 0;
    if (ws_size > fixed) availC = (long long)((ws_size - fixed) / 512);   // 256 f16/edge
    int C = (availC > NEDGE) ? NEDGE : (int)availC;
    C &= ~127;                     // multiple of 128 (msg block) and 64 (h2 block)
    if (C < 128) return;           // workspace too small: clean failure, no fault

    hipMemsetAsync(deg, 0, (size_t)NNODE * 4, stream);
    hipMemsetAsync(agg, 0, (size_t)NNODE * W32 * 4, stream);

    pack_k1<<<40, 256, 0, stream>>>(k1w, k1p);
    pack_k2<<<320, 256, 0, stream>>>(k2w, k2p);
    pack_k3<<<1280, 256, 0, stream>>>(k3w, k3p);

    h0_kernel<<<NNODE * W32 / 256, 256, 0, stream>>>(x, fc1w, fc1b, hA);
    deg_kernel<<<(NEDGE + 255) / 256, 256, 0, stream>>>(ei, deg);

    const bool full = (C == NEDGE);
    if (full)
        h2_kernel<<<NEDGE / 64, 256, 0, stream>>>(ea, k1p, k1b, k2p, k2b, h2b, 0);

    float* hcur = hA; float* hnext = hB;
    for (int d = 0; d < 4; ++d) {
        for (int es = 0; es < NEDGE; es += C) {
            int ce = (NEDGE - es < C) ? (NEDGE - es) : C;   // multiple of 128
            if (!full)
                h2_kernel<<<ce / 64, 256, 0, stream>>>(ea, k1p, k1b, k2p, k2b, h2b, es);
            msg_fused<<<ce / 128, 256, 0, stream>>>(ei, h2b, k3p, k3b, hcur, agg, es);
        }
        update_kernel<<<NNODE / 8, 256, 0, stream>>>(hcur, hnext, agg, deg, rootw, convb);
        float* tmp = hcur; hcur = hnext; hnext = tmp;
    }
    out_kernel<<<(NNODE + 255) / 256, 256, 0, stream>>>(hcur, fc2w, fc2b, out);
}